// Round 2
// baseline (144.742 us; speedup 1.0000x reference)
//
#include <hip/hip_runtime.h>

// PhenoRotary3DPositionalEncoder
// x: (16, 8192, 6) fp32 in [0,1)  ->  enc: (16, 8192, 256) fp32
//
// Math (derived from reference):
//   F = 42 freq bands, but even index 2f and odd index 2f+1 share
//   dim_t = 10000^(f/21), f in [0,21).
//   For half-dim index k in [0,128):
//     k < 2           -> pad: sin(0)=0, cos(0)=1 -> enc pair = (1, 1)
//     k >= 2, j = k-2 -> coord = j/21, f = j%21
//        a = x[pos*6+coord] * (20*pi) * 10000^(-f/21)
//        enc[pos*256 + 2k]   = cos(a) + sin(a)
//        enc[pos*256 + 2k+1] = cos(a) - sin(a)
//
// One thread per float4 (two adjacent pairs) -> 16B coalesced stores.

#define TWENTY_PI          62.83185307179586f
#define LOG2_10000_OVER_21 0.6327482085499738f

__global__ __launch_bounds__(256) void pheno_rotary_pe_kernel(
        const float* __restrict__ x,
        float4* __restrict__ out,
        int npos) {
    int idx = blockIdx.x * blockDim.x + threadIdx.x;  // one float4 per thread
    int pos = idx >> 6;          // 64 float4 per position
    int t   = idx & 63;
    if (pos >= npos) return;

    const float* xp = x + pos * 6;

    float vals[4];
#pragma unroll
    for (int q = 0; q < 2; ++q) {
        int k = 2 * t + q;       // half-dim index 0..127
        float even, odd;
        if (k < 2) {
            even = 1.0f;
            odd  = 1.0f;
        } else {
            int j = k - 2;
            int coord = j / 21;              // magic-mul at -O3
            int f = j - coord * 21;
            float scale = TWENTY_PI *
                __builtin_amdgcn_exp2f(-LOG2_10000_OVER_21 * (float)f);
            float a = xp[coord] * scale;
            float s = __sinf(a);
            float c = __cosf(a);
            even = c + s;
            odd  = c - s;
        }
        vals[2 * q]     = even;
        vals[2 * q + 1] = odd;
    }

    float4 o;
    o.x = vals[0]; o.y = vals[1]; o.z = vals[2]; o.w = vals[3];
    out[idx] = o;
}

extern "C" void kernel_launch(void* const* d_in, const int* in_sizes, int n_in,
                              void* d_out, int out_size, void* d_ws, size_t ws_size,
                              hipStream_t stream) {
    const float* x = (const float*)d_in[0];
    float4* out = (float4*)d_out;

    int npos = in_sizes[0] / 6;          // 16 * 8192 = 131072
    int nthreads = npos * 64;            // one float4 each
    int block = 256;
    int grid = (nthreads + block - 1) / block;

    pheno_rotary_pe_kernel<<<grid, block, 0, stream>>>(x, out, npos);
}

// Round 4
// 143.919 us; speedup vs baseline: 1.0057x; 1.0057x over previous
//
#include <hip/hip_runtime.h>

// PhenoRotary3DPositionalEncoder
// x: (16, 8192, 6) fp32 in [0,1)  ->  enc: (16, 8192, 256) fp32
//
// For half-dim index k in [0,128):
//   k < 2  -> pad: (1, 1)
//   k >= 2 -> j=k-2, coord=j/21, f=j%21
//             a = x[pos*6+coord] * 20*pi * 10000^(-f/21)
//             enc[2k]   = cos(a)+sin(a) = sqrt2 * sin(a + pi/4)
//             enc[2k+1] = cos(a)-sin(a) = sqrt2 * cos(a + pi/4)
// In revolutions: r = fract(x * s_rev + 1/8), s_rev = 10 * 10000^(-f/21);
// pad falls out with s_rev=0, coord=0: r=1/8 -> sqrt2*sin(pi/4)=1, sqrt2*cos(pi/4)=1.
//
// Per-k (s_rev, coord) is position-independent: built once per block in LDS,
// read as one ds_read_b128 per thread (16B/lane stride = 2-way = free).
// One thread per output float4 -> 16B coalesced nontemporal stores.

#define LOG2_10000_OVER_21 0.6327482085499738f
#define SQRT2              1.4142135623730951f

typedef float v4f __attribute__((ext_vector_type(4)));

__global__ __launch_bounds__(256) void pheno_rotary_pe_kernel(
        const float* __restrict__ x,
        v4f* __restrict__ out,
        int npos) {
    __shared__ float2 tbl[128];   // {s_rev, coord bits}

    int tid = threadIdx.x;
    if (tid < 128) {
        float s = 0.0f;
        int   c = 0;
        if (tid >= 2) {
            int j = tid - 2;
            c = j / 21;                    // magic-mul at -O3
            int f = j - 21 * c;
            s = 10.0f * __builtin_amdgcn_exp2f(-LOG2_10000_OVER_21 * (float)f);
        }
        tbl[tid] = make_float2(s, __int_as_float(c));
    }
    __syncthreads();

    int idx = blockIdx.x * 256 + tid;     // one float4 per thread
    int pos = idx >> 6;                   // 64 float4 per position
    if (pos >= npos) return;

    // entries 2t, 2t+1 packed as one v4f: {s0, c0, s1, c1}
    v4f e = ((const v4f*)tbl)[idx & 63];
    const float* xp = x + pos * 6;

    float r0 = __builtin_amdgcn_fractf(
                   fmaf(xp[__float_as_int(e.y)], e.x, 0.125f));
    float r1 = __builtin_amdgcn_fractf(
                   fmaf(xp[__float_as_int(e.w)], e.z, 0.125f));

    v4f o;
    o.x = SQRT2 * __builtin_amdgcn_sinf(r0);
    o.y = SQRT2 * __builtin_amdgcn_cosf(r0);
    o.z = SQRT2 * __builtin_amdgcn_sinf(r1);
    o.w = SQRT2 * __builtin_amdgcn_cosf(r1);

    __builtin_nontemporal_store(o, &out[idx]);
}

extern "C" void kernel_launch(void* const* d_in, const int* in_sizes, int n_in,
                              void* d_out, int out_size, void* d_ws, size_t ws_size,
                              hipStream_t stream) {
    const float* x = (const float*)d_in[0];
    v4f* out = (v4f*)d_out;

    int npos = in_sizes[0] / 6;          // 16 * 8192 = 131072
    int nthreads = npos * 64;            // one float4 each
    int block = 256;
    int grid = (nthreads + block - 1) / block;

    pheno_rotary_pe_kernel<<<grid, block, 0, stream>>>(x, out, npos);
}

// Round 5
// 137.895 us; speedup vs baseline: 1.0497x; 1.0437x over previous
//
#include <hip/hip_runtime.h>

// PhenoRotary3DPositionalEncoder
// x: (16, 8192, 6) fp32 in [0,1)  ->  enc: (16, 8192, 256) fp32
//
// For half-dim index k in [0,128):
//   k < 2  -> pad: (1, 1)
//   k >= 2 -> j=k-2, coord=j/21, f=j%21
//             a = x[pos*6+coord] * 20*pi * 10000^(-f/21)
//             enc[2k]   = cos(a)+sin(a) = sqrt2 * sin(a + pi/4)
//             enc[2k+1] = cos(a)-sin(a) = sqrt2 * cos(a + pi/4)
// In revolutions: r = fract(x * s_rev + 1/8), s_rev = 10 * 10000^(-f/21);
// pad falls out with s_rev=0, coord=0: r=1/8 -> sqrt2*sin(pi/4)=1, sqrt2*cos(pi/4)=1.
//
// Per-k (s_rev, coord) is position-independent: built once per block in LDS,
// read as one ds_read_b128 per thread (16B/lane stride = 2-way = free).
// One thread per output float4 -> 16B coalesced stores.
// NO nontemporal hint: d_out (134 MB) fits in the 256 MB Infinity Cache, so
// plain stores can be absorbed by L3 instead of draining at the HBM ceiling.

#define LOG2_10000_OVER_21 0.6327482085499738f
#define SQRT2              1.4142135623730951f

typedef float v4f __attribute__((ext_vector_type(4)));

__global__ __launch_bounds__(256) void pheno_rotary_pe_kernel(
        const float* __restrict__ x,
        v4f* __restrict__ out,
        int npos) {
    __shared__ float2 tbl[128];   // {s_rev, coord bits}

    int tid = threadIdx.x;
    if (tid < 128) {
        float s = 0.0f;
        int   c = 0;
        if (tid >= 2) {
            int j = tid - 2;
            c = j / 21;                    // magic-mul at -O3
            int f = j - 21 * c;
            s = 10.0f * __builtin_amdgcn_exp2f(-LOG2_10000_OVER_21 * (float)f);
        }
        tbl[tid] = make_float2(s, __int_as_float(c));
    }
    __syncthreads();

    int idx = blockIdx.x * 256 + tid;     // one float4 per thread
    int pos = idx >> 6;                   // 64 float4 per position
    if (pos >= npos) return;

    // entries 2t, 2t+1 packed as one v4f: {s0, c0, s1, c1}
    v4f e = ((const v4f*)tbl)[idx & 63];
    const float* xp = x + pos * 6;

    float r0 = __builtin_amdgcn_fractf(
                   fmaf(xp[__float_as_int(e.y)], e.x, 0.125f));
    float r1 = __builtin_amdgcn_fractf(
                   fmaf(xp[__float_as_int(e.w)], e.z, 0.125f));

    v4f o;
    o.x = SQRT2 * __builtin_amdgcn_sinf(r0);
    o.y = SQRT2 * __builtin_amdgcn_cosf(r0);
    o.z = SQRT2 * __builtin_amdgcn_sinf(r1);
    o.w = SQRT2 * __builtin_amdgcn_cosf(r1);

    out[idx] = o;
}

extern "C" void kernel_launch(void* const* d_in, const int* in_sizes, int n_in,
                              void* d_out, int out_size, void* d_ws, size_t ws_size,
                              hipStream_t stream) {
    const float* x = (const float*)d_in[0];
    v4f* out = (v4f*)d_out;

    int npos = in_sizes[0] / 6;          // 16 * 8192 = 131072
    int nthreads = npos * 64;            // one float4 each
    int block = 256;
    int grid = (nthreads + block - 1) / block;

    pheno_rotary_pe_kernel<<<grid, block, 0, stream>>>(x, out, npos);
}

// Round 6
// 132.754 us; speedup vs baseline: 1.0903x; 1.0387x over previous
//
#include <hip/hip_runtime.h>

// PhenoRotary3DPositionalEncoder
// x: (16, 8192, 6) fp32 in [0,1)  ->  enc: (16, 8192, 256) fp32
//
// For half-dim index k in [0,128):
//   k < 2  -> pad: (1, 1)
//   k >= 2 -> j=k-2, coord=j/21, f=j%21
//             a = x[pos*6+coord] * 20*pi * 10000^(-f/21)
//             enc[2k]   = cos(a)+sin(a) = sqrt2 * sin(a + pi/4)
//             enc[2k+1] = cos(a)-sin(a) = sqrt2 * cos(a + pi/4)
// In revolutions: r = fract(x * s_rev + 1/8), s_rev = 10 * 10000^(-f/21);
// pad (k<2) falls out with s_rev=0, coordoff=0: r=1/8 -> both outputs 1.
//
// Per-k (s_rev, coord byte offset) table built once per block in LDS.
// Each thread produces TWO output float4s (quads u and u+32 of one position):
// halves per-thread fixed overhead (index math, x base address). Grid is
// exact (131072 pos * 32 threads = 16384 * 256) -> no bounds check.
// Plain (cacheable) stores: d_out (134 MB) fits in 256 MB Infinity Cache.

#define LOG2_10000_OVER_21 0.6327482085499738f
#define SQRT2              1.4142135623730951f

typedef float v4f __attribute__((ext_vector_type(4)));

__global__ __launch_bounds__(256) void pheno_rotary_pe_kernel(
        const float* __restrict__ x,
        v4f* __restrict__ out) {
    __shared__ float2 tbl[128];   // {s_rev, coord*4 as int bits}

    int tid = threadIdx.x;
    if (tid < 128) {
        float s = 0.0f;
        int   c4 = 0;
        if (tid >= 2) {
            int j = tid - 2;
            int c = j / 21;                 // magic-mul at -O3
            int f = j - 21 * c;
            c4 = c * 4;                     // byte offset into x row
            s = 10.0f * __builtin_amdgcn_exp2f(-LOG2_10000_OVER_21 * (float)f);
        }
        tbl[tid] = make_float2(s, __int_as_float(c4));
    }
    __syncthreads();

    int idx = blockIdx.x * 256 + tid;
    int u   = idx & 31;           // quad slot 0..31 (second quad = u+32)
    int pos = idx >> 5;

    // quad u covers half-dims 2u,2u+1: table entry {s0, off0, s1, off1}
    const v4f* t4 = (const v4f*)tbl;
    v4f e0 = t4[u];
    v4f e1 = t4[u + 32];

    const char* xb = (const char*)x + pos * 24;   // 6 floats per position
    float x00 = *(const float*)(xb + __float_as_int(e0.y));
    float x01 = *(const float*)(xb + __float_as_int(e0.w));
    float x10 = *(const float*)(xb + __float_as_int(e1.y));
    float x11 = *(const float*)(xb + __float_as_int(e1.w));

    float r00 = __builtin_amdgcn_fractf(fmaf(x00, e0.x, 0.125f));
    float r01 = __builtin_amdgcn_fractf(fmaf(x01, e0.z, 0.125f));
    float r10 = __builtin_amdgcn_fractf(fmaf(x10, e1.x, 0.125f));
    float r11 = __builtin_amdgcn_fractf(fmaf(x11, e1.z, 0.125f));

    v4f o0, o1;
    o0.x = SQRT2 * __builtin_amdgcn_sinf(r00);
    o0.y = SQRT2 * __builtin_amdgcn_cosf(r00);
    o0.z = SQRT2 * __builtin_amdgcn_sinf(r01);
    o0.w = SQRT2 * __builtin_amdgcn_cosf(r01);
    o1.x = SQRT2 * __builtin_amdgcn_sinf(r10);
    o1.y = SQRT2 * __builtin_amdgcn_cosf(r10);
    o1.z = SQRT2 * __builtin_amdgcn_sinf(r11);
    o1.w = SQRT2 * __builtin_amdgcn_cosf(r11);

    v4f* ob = out + pos * 64 + u;
    ob[0]  = o0;
    ob[32] = o1;   // +512 B -> offset immediate
}

extern "C" void kernel_launch(void* const* d_in, const int* in_sizes, int n_in,
                              void* d_out, int out_size, void* d_ws, size_t ws_size,
                              hipStream_t stream) {
    const float* x = (const float*)d_in[0];
    v4f* out = (v4f*)d_out;

    int npos = in_sizes[0] / 6;          // 16 * 8192 = 131072
    int nthreads = npos * 32;            // two float4 each
    int block = 256;
    int grid = (nthreads + block - 1) / block;   // exact: 16384

    pheno_rotary_pe_kernel<<<grid, block, 0, stream>>>(x, out);
}